// Round 9
// baseline (482.358 us; speedup 1.0000x reference)
//
#include <hip/hip_runtime.h>

#define EPS 1e-7f
#define NCH 29
// Per-channel weight block in LDS: 108 floats (432 B, 16B-aligned), offsets:
//  W0[7][5]@0(35)  b0@36(5)  W1[5][4]@44(20)  b1@64(4)
//  W2[4][4]@68(16) b2@84(4)  W3[4][3]@88(12)  b3@100(3)
#define CHW 108
#define WLDS_FLOATS (2 * NCH * CHW)   // 6264 floats = 25056 B

__global__ __launch_bounds__(256, 4) void lps_kernel(
    const float* __restrict__ tau, const float* __restrict__ mu, const float* __restrict__ mu_bar,
    const float* __restrict__ lw, const float* __restrict__ h2o, const float* __restrict__ o3,
    const float* __restrict__ co2, const float* __restrict__ uu, const float* __restrict__ n2o,
    const float* __restrict__ ch4,
    const float* __restrict__ Wd0, const float* __restrict__ bd0,
    const float* __restrict__ Wf0, const float* __restrict__ bf0,
    const float* __restrict__ Wd1, const float* __restrict__ bd1,
    const float* __restrict__ Wf1, const float* __restrict__ bf1,
    const float* __restrict__ Wd2, const float* __restrict__ bd2,
    const float* __restrict__ Wf2, const float* __restrict__ bf2,
    const float* __restrict__ Wd3, const float* __restrict__ bd3,
    const float* __restrict__ Wf3, const float* __restrict__ bf3,
    float* __restrict__ out, int N)
{
    __shared__ float wlds[WLDS_FLOATS];            // 25056 B: remapped weights
    __shared__ __align__(16) float4 sbuf[4 * 232]; // 14848 B: per-wave staging [4 samp][58 f4]

    const int tid = threadIdx.x;

    // ---- one-time weight stage+remap into per-channel blocks ----
    auto seg = [&](const float* __restrict__ src, int len, int nbase, int off) {
        for (int i = tid; i < NCH * len; i += 256) {
            const int c = i / len, j = i - c * len;
            wlds[(nbase + c) * CHW + off + j] = src[i];
        }
    };
    seg(Wd0, 35, 0, 0);   seg(bd0, 5, 0, 36);  seg(Wd1, 20, 0, 44);  seg(bd1, 4, 0, 64);
    seg(Wd2, 16, 0, 68);  seg(bd2, 4, 0, 84);  seg(Wd3, 12, 0, 88);  seg(bd3, 3, 0, 100);
    seg(Wf0, 35, NCH, 0); seg(bf0, 5, NCH, 36); seg(Wf1, 20, NCH, 44); seg(bf1, 4, NCH, 64);
    seg(Wf2, 16, NCH, 68); seg(bf2, 4, NCH, 84); seg(Wf3, 12, NCH, 88); seg(bf3, 3, NCH, 100);
    __syncthreads();   // only block-wide barrier (prologue)

    const int lane  = tid & 63;
    const int wid   = __builtin_amdgcn_readfirstlane(tid >> 6);
    const int c_grp = lane >> 2;      // 0..15
    const int sl    = lane & 3;       // sample-in-group 0..3

    float4* const swv = sbuf + wid * 232;            // wave-private staging
    float4* const out4 = (float4*)out;
    const long long wsbase = (long long)blockIdx.x * 256 + wid * 64;  // wave's first sample
    const long long n58 = (long long)N * 58;

    for (int g = 0; g < 16; ++g) {
        const long long sg = wsbase + g * 4 + sl;
        const int i0 = (sg < N) ? (int)sg : (N - 1);

        const float rmu  = __builtin_amdgcn_rcpf(mu[i0] + EPS);
        const float rmub = __builtin_amdgcn_rcpf(mu_bar[i0] + EPS);
        const float nrmu = -rmu, nrmub = -rmub;

        float cons[7];
        cons[0] = lw[i0]; cons[1] = h2o[i0]; cons[2] = o3[i0]; cons[3] = co2[i0];
        cons[4] = uu[i0]; cons[5] = n2o[i0]; cons[6] = ch4[i0];
        float xd[7], xf[7];
#pragma unroll
        for (int f = 0; f < 7; ++f) { xd[f] = cons[f] * rmu; xf[f] = cons[f] * rmub; }

        // ---- two channel visits: c = c_grp, c_grp+16 ----
#pragma unroll
        for (int v = 0; v < 2; ++v) {
            const int c = c_grp + 16 * v;
            if (c < NCH) {
                const float tv = tau[(size_t)i0 * NCH + c];
                const float td = __expf(tv * nrmu);
                const float tf = __expf(tv * nrmub);

                float e[2][3];
#pragma unroll
                for (int n = 0; n < 2; ++n) {
                    const float* wb = wlds + (n * NCH + c) * CHW;
                    const float* x  = n ? xf : xd;
                    float h0[5];
#pragma unroll
                    for (int h = 0; h < 5; ++h) {
                        float a = wb[36 + h];
#pragma unroll
                        for (int f = 0; f < 7; ++f) a = fmaf(x[f], wb[f * 5 + h], a);
                        h0[h] = fmaxf(a, 0.0f);
                    }
                    float h1[4];
#pragma unroll
                    for (int k = 0; k < 4; ++k) {
                        float a = wb[64 + k];
#pragma unroll
                        for (int f = 0; f < 5; ++f) a = fmaf(h0[f], wb[44 + f * 4 + k], a);
                        h1[k] = fmaxf(a, 0.0f);
                    }
                    float h2[4];
#pragma unroll
                    for (int k = 0; k < 4; ++k) {
                        float a = wb[84 + k];
#pragma unroll
                        for (int f = 0; f < 4; ++f) a = fmaf(h1[f], wb[68 + f * 4 + k], a);
                        h2[k] = fmaxf(a, 0.0f);
                    }
                    float l[3];
#pragma unroll
                    for (int k = 0; k < 3; ++k) {
                        float a = wb[100 + k];
#pragma unroll
                        for (int f = 0; f < 4; ++f) a = fmaf(h2[f], wb[88 + f * 3 + k], a);
                        l[k] = a;
                    }
                    const float m  = fmaxf(l[0], fmaxf(l[1], l[2]));
                    const float e0 = __expf(l[0] - m);
                    const float e1 = __expf(l[1] - m);
                    const float e2 = __expf(l[2] - m);
                    const float rs = __builtin_amdgcn_rcpf(e0 + e1 + e2);
                    e[n][0] = e0 * rs; e[n][1] = e1 * rs; e[n][2] = e2 * rs;
                }

                swv[sl * 58 + c * 2]     = make_float4(td, tf, e[0][0], e[0][1]);
                swv[sl * 58 + c * 2 + 1] = make_float4(e[0][2], e[1][0], e[1][1], e[1][2]);
            }
        }

        // ---- wave-private flush: 4 samples x 928 B, linear & contiguous ----
        // (compiler inserts lgkmcnt for ds_write->ds_read dep; in-wave only,
        //  no barrier. Stores trickle out continuously across all waves.)
        const long long g4 = (wsbase + g * 4) * 58;
#pragma unroll
        for (int k = 0; k < 4; ++k) {
            const int idx = lane + k * 64;
            const long long o = g4 + idx;
            if (idx < 232 && o < n58) out4[o] = swv[idx];
        }
    }
}

extern "C" void kernel_launch(void* const* d_in, const int* in_sizes, int n_in,
                              void* d_out, int out_size, void* d_ws, size_t ws_size,
                              hipStream_t stream) {
    const float* tau    = (const float*)d_in[0];
    const float* mu     = (const float*)d_in[1];
    const float* mu_bar = (const float*)d_in[2];
    const float* lw     = (const float*)d_in[3];
    const float* h2o    = (const float*)d_in[4];
    const float* o3     = (const float*)d_in[5];
    const float* co2    = (const float*)d_in[6];
    const float* uu     = (const float*)d_in[7];
    const float* n2o    = (const float*)d_in[8];
    const float* ch4    = (const float*)d_in[9];

    const float* Wd0 = (const float*)d_in[10];
    const float* bd0 = (const float*)d_in[11];
    const float* Wf0 = (const float*)d_in[12];
    const float* bf0 = (const float*)d_in[13];
    const float* Wd1 = (const float*)d_in[14];
    const float* bd1 = (const float*)d_in[15];
    const float* Wf1 = (const float*)d_in[16];
    const float* bf1 = (const float*)d_in[17];
    const float* Wd2 = (const float*)d_in[18];
    const float* bd2 = (const float*)d_in[19];
    const float* Wf2 = (const float*)d_in[20];
    const float* bf2 = (const float*)d_in[21];
    const float* Wd3 = (const float*)d_in[22];
    const float* bd3 = (const float*)d_in[23];
    const float* Wf3 = (const float*)d_in[24];
    const float* bf3 = (const float*)d_in[25];

    float* out = (float*)d_out;
    int N = in_sizes[1];  // mu has N elements

    int blocks = (N + 255) / 256;
    lps_kernel<<<blocks, 256, 0, stream>>>(
        tau, mu, mu_bar, lw, h2o, o3, co2, uu, n2o, ch4,
        Wd0, bd0, Wf0, bf0, Wd1, bd1, Wf1, bf1,
        Wd2, bd2, Wf2, bf2, Wd3, bd3, Wf3, bf3,
        out, N);
}

// Round 10
// 104.208 us; speedup vs baseline: 4.6288x; 4.6288x over previous
//
#include <hip/hip_runtime.h>

#define EPS 1e-7f
#define NCH 29
#define SPB 128          // samples per block (2 per lane)
#define ROWF4 59         // padded float4 stride per sample in obuf

// MLP sizes: 7 -> 5 -> 4 -> 4 -> 3, per-channel weights.
// W0: [c][7][5]  b0: [c][5]
// W1: [c][5][4]  b1: [c][4]
// W2: [c][4][4]  b2: [c][4]
// W3: [c][4][3]  b3: [c][3]
// Output row per sample: 58 float4; slot 2c = (td, tf, ed0, ed1),
// slot 2c+1 = (ed2, ef0, ef1, ef2).

// Barrier ordering LDS/SMEM only (lgkmcnt), not global loads/stores.
__device__ __forceinline__ void barrier_lds_only() {
    asm volatile("s_waitcnt lgkmcnt(0)\n\ts_barrier" ::: "memory");
}

__global__ __launch_bounds__(1024, 4) void lps_kernel(
    const float* __restrict__ tau, const float* __restrict__ mu, const float* __restrict__ mu_bar,
    const float* __restrict__ lw, const float* __restrict__ h2o, const float* __restrict__ o3,
    const float* __restrict__ co2, const float* __restrict__ uu, const float* __restrict__ n2o,
    const float* __restrict__ ch4,
    const float* __restrict__ Wd0, const float* __restrict__ bd0,
    const float* __restrict__ Wf0, const float* __restrict__ bf0,
    const float* __restrict__ Wd1, const float* __restrict__ bd1,
    const float* __restrict__ Wf1, const float* __restrict__ bf1,
    const float* __restrict__ Wd2, const float* __restrict__ bd2,
    const float* __restrict__ Wf2, const float* __restrict__ bf2,
    const float* __restrict__ Wd3, const float* __restrict__ bd3,
    const float* __restrict__ Wf3, const float* __restrict__ bf3,
    float* __restrict__ out, int N)
{
    __shared__ __align__(16) float4 obuf[SPB * ROWF4];   // 120832 B, 1 block/CU

    const int tid  = threadIdx.x;
    const int lane = tid & 63;
    const int wid  = __builtin_amdgcn_readfirstlane(tid >> 6);   // 0..15

    const long long base = (long long)blockIdx.x * SPB;
    const int s0 = (int)base + lane;
    const int s1 = s0 + 64;
    const int i0 = (s0 < N) ? s0 : (N - 1);
    const int i1 = (s1 < N) ? s1 : (N - 1);
    const int l0 = lane, l1 = lane + 64;     // local sample slots

    // ---- per-lane input state, loaded once per block ----
    const float rmu0  = __builtin_amdgcn_rcpf(mu[i0] + EPS);
    const float rmu1  = __builtin_amdgcn_rcpf(mu[i1] + EPS);
    const float rmub0 = __builtin_amdgcn_rcpf(mu_bar[i0] + EPS);
    const float rmub1 = __builtin_amdgcn_rcpf(mu_bar[i1] + EPS);

    float cons0[7], cons1[7];
    cons0[0] = lw[i0];  cons1[0] = lw[i1];
    cons0[1] = h2o[i0]; cons1[1] = h2o[i1];
    cons0[2] = o3[i0];  cons1[2] = o3[i1];
    cons0[3] = co2[i0]; cons1[3] = co2[i1];
    cons0[4] = uu[i0];  cons1[4] = uu[i1];
    cons0[5] = n2o[i0]; cons1[5] = n2o[i1];
    cons0[6] = ch4[i0]; cons1[6] = ch4[i1];

    // ---- 4 role-phases, NO barriers between (waves desync) ----
#pragma unroll
    for (int p = 0; p < 4; ++p) {
        const int r = p * 16 + wid;          // wave-uniform role id
        if (r < 2 * NCH) {
            const int c  = r >> 1;           // channel 0..28
            const int ty = r & 1;            // 0: direct MLP, 1: diffuse MLP

            const float* __restrict__ W0 = (ty ? Wf0 : Wd0) + c * 35;
            const float* __restrict__ B0 = (ty ? bf0 : bd0) + c * 5;
            const float* __restrict__ W1 = (ty ? Wf1 : Wd1) + c * 20;
            const float* __restrict__ B1 = (ty ? bf1 : bd1) + c * 4;
            const float* __restrict__ W2 = (ty ? Wf2 : Wd2) + c * 16;
            const float* __restrict__ B2 = (ty ? bf2 : bd2) + c * 4;
            const float* __restrict__ W3 = (ty ? Wf3 : Wd3) + c * 12;
            const float* __restrict__ B3 = (ty ? bf3 : bd3) + c * 3;

            const float rs0 = ty ? rmub0 : rmu0;
            const float rs1 = ty ? rmub1 : rmu1;

            float x0[7], x1[7];
#pragma unroll
            for (int f = 0; f < 7; ++f) { x0[f] = cons0[f] * rs0; x1[f] = cons1[f] * rs1; }

            // ---- one MLP, two samples interleaved (2-way ILP per weight) ----
            float h0a[5], h0b[5];
#pragma unroll
            for (int h = 0; h < 5; ++h) {
                float a = B0[h], b = B0[h];
#pragma unroll
                for (int f = 0; f < 7; ++f) {
                    const float w = W0[f * 5 + h];
                    a = fmaf(x0[f], w, a);
                    b = fmaf(x1[f], w, b);
                }
                h0a[h] = fmaxf(a, 0.0f); h0b[h] = fmaxf(b, 0.0f);
            }
            float h1a[4], h1b[4];
#pragma unroll
            for (int k = 0; k < 4; ++k) {
                float a = B1[k], b = B1[k];
#pragma unroll
                for (int f = 0; f < 5; ++f) {
                    const float w = W1[f * 4 + k];
                    a = fmaf(h0a[f], w, a);
                    b = fmaf(h0b[f], w, b);
                }
                h1a[k] = fmaxf(a, 0.0f); h1b[k] = fmaxf(b, 0.0f);
            }
            float h2a[4], h2b[4];
#pragma unroll
            for (int k = 0; k < 4; ++k) {
                float a = B2[k], b = B2[k];
#pragma unroll
                for (int f = 0; f < 4; ++f) {
                    const float w = W2[f * 4 + k];
                    a = fmaf(h1a[f], w, a);
                    b = fmaf(h1b[f], w, b);
                }
                h2a[k] = fmaxf(a, 0.0f); h2b[k] = fmaxf(b, 0.0f);
            }
            float la[3], lb[3];
#pragma unroll
            for (int k = 0; k < 3; ++k) {
                float a = B3[k], b = B3[k];
#pragma unroll
                for (int f = 0; f < 4; ++f) {
                    const float w = W3[f * 3 + k];
                    a = fmaf(h2a[f], w, a);
                    b = fmaf(h2b[f], w, b);
                }
                la[k] = a; lb[k] = b;
            }
            const float ma = fmaxf(la[0], fmaxf(la[1], la[2]));
            const float mb = fmaxf(lb[0], fmaxf(lb[1], lb[2]));
            const float ea0 = __expf(la[0] - ma), ea1 = __expf(la[1] - ma), ea2 = __expf(la[2] - ma);
            const float eb0 = __expf(lb[0] - mb), eb1 = __expf(lb[1] - mb), eb2 = __expf(lb[2] - mb);
            const float ra = __builtin_amdgcn_rcpf(ea0 + ea1 + ea2);
            const float rb = __builtin_amdgcn_rcpf(eb0 + eb1 + eb2);

            if (ty == 0) {
                // direct: also transmittances; write slot 2c (f4) + ed2 (word 0 of 2c+1)
                const float tv0 = tau[(size_t)i0 * NCH + c];
                const float tv1 = tau[(size_t)i1 * NCH + c];
                const float td0 = __expf(-tv0 * rmu0), tf0 = __expf(-tv0 * rmub0);
                const float td1 = __expf(-tv1 * rmu1), tf1 = __expf(-tv1 * rmub1);

                obuf[l0 * ROWF4 + 2 * c] = make_float4(td0, tf0, ea0 * ra, ea1 * ra);
                ((float*)&obuf[l0 * ROWF4 + 2 * c + 1])[0] = ea2 * ra;
                obuf[l1 * ROWF4 + 2 * c] = make_float4(td1, tf1, eb0 * rb, eb1 * rb);
                ((float*)&obuf[l1 * ROWF4 + 2 * c + 1])[0] = eb2 * rb;
            } else {
                // diffuse: words 1..3 of slot 2c+1
                float* q0 = (float*)&obuf[l0 * ROWF4 + 2 * c + 1];
                q0[1] = ea0 * ra; q0[2] = ea1 * ra; q0[3] = ea2 * ra;
                float* q1 = (float*)&obuf[l1 * ROWF4 + 2 * c + 1];
                q1[1] = eb0 * rb; q1[2] = eb1 * rb; q1[3] = eb2 * rb;
            }
        }
    }

    barrier_lds_only();

    // ---- single contiguous flush: 128 samples x 928 B, full-line coalesced ----
    float4* out4 = (float4*)out;
    int nsamp = N - (int)base;
    if (nsamp > SPB) nsamp = SPB;
    if (nsamp > 0) {
        const int tot = nsamp * 58;
        const long long ob = base * 58;
        for (int i = tid; i < tot; i += 1024) {
            const int s = i / 58, rr = i - s * 58;
            out4[ob + i] = obuf[s * ROWF4 + rr];
        }
    }
}

extern "C" void kernel_launch(void* const* d_in, const int* in_sizes, int n_in,
                              void* d_out, int out_size, void* d_ws, size_t ws_size,
                              hipStream_t stream) {
    const float* tau    = (const float*)d_in[0];
    const float* mu     = (const float*)d_in[1];
    const float* mu_bar = (const float*)d_in[2];
    const float* lw     = (const float*)d_in[3];
    const float* h2o    = (const float*)d_in[4];
    const float* o3     = (const float*)d_in[5];
    const float* co2    = (const float*)d_in[6];
    const float* uu     = (const float*)d_in[7];
    const float* n2o    = (const float*)d_in[8];
    const float* ch4    = (const float*)d_in[9];

    const float* Wd0 = (const float*)d_in[10];
    const float* bd0 = (const float*)d_in[11];
    const float* Wf0 = (const float*)d_in[12];
    const float* bf0 = (const float*)d_in[13];
    const float* Wd1 = (const float*)d_in[14];
    const float* bd1 = (const float*)d_in[15];
    const float* Wf1 = (const float*)d_in[16];
    const float* bf1 = (const float*)d_in[17];
    const float* Wd2 = (const float*)d_in[18];
    const float* bd2 = (const float*)d_in[19];
    const float* Wf2 = (const float*)d_in[20];
    const float* bf2 = (const float*)d_in[21];
    const float* Wd3 = (const float*)d_in[22];
    const float* bd3 = (const float*)d_in[23];
    const float* Wf3 = (const float*)d_in[24];
    const float* bf3 = (const float*)d_in[25];

    float* out = (float*)d_out;
    int N = in_sizes[1];  // mu has N elements

    int blocks = (N + SPB - 1) / SPB;
    lps_kernel<<<blocks, 1024, 0, stream>>>(
        tau, mu, mu_bar, lw, h2o, o3, co2, uu, n2o, ch4,
        Wd0, bd0, Wf0, bf0, Wd1, bd1, Wf1, bf1,
        Wd2, bd2, Wf2, bf2, Wd3, bd3, Wf3, bf3,
        out, N);
}

// Round 11
// 81.375 us; speedup vs baseline: 5.9276x; 1.2806x over previous
//
#include <hip/hip_runtime.h>

#define EPS 1e-7f
#define NCH 29
#define SPB 128          // samples per block: 64 lanes x 2 packed (group0, group1)
#define ROWA 17          // padded float4 stride per sample in chunk staging buffer

// MLP sizes: 7 -> 5 -> 4 -> 4 -> 3, per-channel weights.
// W0: [c][7][5]  b0: [c][5]
// W1: [c][5][4]  b1: [c][4]
// W2: [c][4][4]  b2: [c][4]
// W3: [c][4][3]  b3: [c][3]

typedef float f32x2 __attribute__((ext_vector_type(2)));

__device__ __forceinline__ f32x2 splat2(float v) { f32x2 r; r.x = v; r.y = v; return r; }
__device__ __forceinline__ f32x2 fma2(f32x2 a, f32x2 b, f32x2 c) {
    return __builtin_elementwise_fma(a, b, c);
}
__device__ __forceinline__ f32x2 max2(f32x2 a, f32x2 b) {
    return __builtin_elementwise_max(a, b);
}
__device__ __forceinline__ f32x2 expc2(f32x2 a) {
    f32x2 r; r.x = __expf(a.x); r.y = __expf(a.y); return r;
}
__device__ __forceinline__ f32x2 rcp2(f32x2 a) {
    f32x2 r; r.x = __builtin_amdgcn_rcpf(a.x); r.y = __builtin_amdgcn_rcpf(a.y); return r;
}

// Barrier ordering LDS traffic only (lgkmcnt), NOT global stores (vmcnt).
// This is the whole point of this round: chunk-k stores stay in flight
// underneath chunk-(k+1) compute; no vmcnt(0) drain anywhere in the kernel.
__device__ __forceinline__ void barrier_lds_only() {
    asm volatile("s_waitcnt lgkmcnt(0)\n\ts_barrier" ::: "memory");
}

// Packed 2-sample MLP: weights wave-uniform (SGPR), data f32x2 -> v_pk_fma_f32.
__device__ __forceinline__ void mlp7p(const f32x2 x[7],
    const float* __restrict__ W0, const float* __restrict__ b0,
    const float* __restrict__ W1, const float* __restrict__ b1,
    const float* __restrict__ W2, const float* __restrict__ b2,
    const float* __restrict__ W3, const float* __restrict__ b3,
    f32x2 e[3])
{
    const f32x2 zero = splat2(0.0f);
    f32x2 h0[5];
#pragma unroll
    for (int h = 0; h < 5; ++h) {
        f32x2 a = splat2(b0[h]);
#pragma unroll
        for (int f = 0; f < 7; ++f) a = fma2(x[f], splat2(W0[f * 5 + h]), a);
        h0[h] = max2(a, zero);
    }
    f32x2 h1[4];
#pragma unroll
    for (int k = 0; k < 4; ++k) {
        f32x2 a = splat2(b1[k]);
#pragma unroll
        for (int h = 0; h < 5; ++h) a = fma2(h0[h], splat2(W1[h * 4 + k]), a);
        h1[k] = max2(a, zero);
    }
    f32x2 h2[4];
#pragma unroll
    for (int k = 0; k < 4; ++k) {
        f32x2 a = splat2(b2[k]);
#pragma unroll
        for (int h = 0; h < 4; ++h) a = fma2(h1[h], splat2(W2[h * 4 + k]), a);
        h2[k] = max2(a, zero);
    }
    f32x2 l[3];
#pragma unroll
    for (int k = 0; k < 3; ++k) {
        f32x2 a = splat2(b3[k]);
#pragma unroll
        for (int h = 0; h < 4; ++h) a = fma2(h2[h], splat2(W3[h * 3 + k]), a);
        l[k] = a;
    }
    f32x2 m = max2(l[0], max2(l[1], l[2]));
    f32x2 e0 = expc2(l[0] - m);
    f32x2 e1 = expc2(l[1] - m);
    f32x2 e2 = expc2(l[2] - m);
    f32x2 rs = rcp2(e0 + e1 + e2);
    e[0] = e0 * rs; e[1] = e1 * rs; e[2] = e2 * rs;
}

__global__ __launch_bounds__(512, 4) void lps_kernel(
    const float* __restrict__ tau, const float* __restrict__ mu, const float* __restrict__ mu_bar,
    const float* __restrict__ lw, const float* __restrict__ h2o, const float* __restrict__ o3,
    const float* __restrict__ co2, const float* __restrict__ uu, const float* __restrict__ n2o,
    const float* __restrict__ ch4,
    const float* __restrict__ Wd0, const float* __restrict__ bd0,
    const float* __restrict__ Wf0, const float* __restrict__ bf0,
    const float* __restrict__ Wd1, const float* __restrict__ bd1,
    const float* __restrict__ Wf1, const float* __restrict__ bf1,
    const float* __restrict__ Wd2, const float* __restrict__ bd2,
    const float* __restrict__ Wf2, const float* __restrict__ bf2,
    const float* __restrict__ Wd3, const float* __restrict__ bd3,
    const float* __restrict__ Wf3, const float* __restrict__ bf3,
    float* __restrict__ out, int N)
{
    __shared__ __align__(16) float4 obuf[SPB * ROWA];   // 34816 B

    const int tid  = threadIdx.x;
    const int lane = tid & 63;
    const int wid  = __builtin_amdgcn_readfirstlane(tid >> 6);   // 0..7

    const long long base = (long long)blockIdx.x * SPB;
    const int s0 = (int)base + lane;
    const int s1 = s0 + 64;
    const int i0 = (s0 < N) ? s0 : (N - 1);
    const int i1 = (s1 < N) ? s1 : (N - 1);

    f32x2 mu2, mub2;
    mu2.x  = mu[i0];      mu2.y  = mu[i1];
    mub2.x = mu_bar[i0];  mub2.y = mu_bar[i1];
    const f32x2 rmu2   = rcp2(mu2 + splat2(EPS));
    const f32x2 rmub2  = rcp2(mub2 + splat2(EPS));
    const f32x2 nrmu2  = -rmu2;
    const f32x2 nrmub2 = -rmub2;

    f32x2 x2d[7], x2f[7];
    {
        f32x2 t;
        t.x = lw[i0];  t.y = lw[i1];  x2d[0] = t * rmu2; x2f[0] = t * rmub2;
        t.x = h2o[i0]; t.y = h2o[i1]; x2d[1] = t * rmu2; x2f[1] = t * rmub2;
        t.x = o3[i0];  t.y = o3[i1];  x2d[2] = t * rmu2; x2f[2] = t * rmub2;
        t.x = co2[i0]; t.y = co2[i1]; x2d[3] = t * rmu2; x2f[3] = t * rmub2;
        t.x = uu[i0];  t.y = uu[i1];  x2d[4] = t * rmu2; x2f[4] = t * rmub2;
        t.x = n2o[i0]; t.y = n2o[i1]; x2d[5] = t * rmu2; x2f[5] = t * rmub2;
        t.x = ch4[i0]; t.y = ch4[i1]; x2d[6] = t * rmu2; x2f[6] = t * rmub2;
    }

    int nsamp = N - (int)base;
    if (nsamp > SPB) nsamp = SPB;
    float4* out4 = (float4*)out;

    // 4 chunk-phases: compute 8 channels -> lgkm barrier -> issue stores ->
    // lgkm barrier -> next compute. Stores never waited on (no vmcnt drain),
    // so chunk k's HBM drain overlaps chunk k+1's compute.
#pragma unroll
    for (int k = 0; k < 4; ++k) {
        const int c = k * 8 + wid;            // wave-uniform channel
        if (c < NCH) {
            f32x2 tau2;
            tau2.x = tau[(size_t)i0 * NCH + c];
            tau2.y = tau[(size_t)i1 * NCH + c];
            const f32x2 td2 = expc2(tau2 * nrmu2);
            const f32x2 tf2 = expc2(tau2 * nrmub2);

            f32x2 ed[3], ef[3];
            mlp7p(x2d, Wd0 + c * 35, bd0 + c * 5, Wd1 + c * 20, bd1 + c * 4,
                       Wd2 + c * 16, bd2 + c * 4, Wd3 + c * 12, bd3 + c * 3, ed);
            mlp7p(x2f, Wf0 + c * 35, bf0 + c * 5, Wf1 + c * 20, bf1 + c * 4,
                       Wf2 + c * 16, bf2 + c * 4, Wf3 + c * 12, bf3 + c * 3, ef);

            const int r = (c - k * 8) * 2;    // local slot 0..15
            obuf[lane * ROWA + r]            = make_float4(td2.x, tf2.x, ed[0].x, ed[1].x);
            obuf[lane * ROWA + r + 1]        = make_float4(ed[2].x, ef[0].x, ef[1].x, ef[2].x);
            obuf[(lane + 64) * ROWA + r]     = make_float4(td2.y, tf2.y, ed[0].y, ed[1].y);
            obuf[(lane + 64) * ROWA + r + 1] = make_float4(ed[2].y, ef[0].y, ef[1].y, ef[2].y);
        }

        barrier_lds_only();

        // issue chunk-k stores (fire-and-forget)
        if (nsamp > 0) {
            if (k < 3) {
                const int tot = nsamp * 16;
                for (int i = tid; i < tot; i += 512) {
                    const int s = i >> 4, rr = i & 15;
                    out4[(base + s) * 58 + k * 16 + rr] = obuf[s * ROWA + rr];
                }
            } else {
                const int tot = nsamp * 10;   // 5 channels -> 10 f4 per sample
                for (int i = tid; i < tot; i += 512) {
                    const int s = i / 10, rr = i - s * 10;
                    out4[(base + s) * 58 + 48 + rr] = obuf[s * ROWA + rr];
                }
            }
        }

        barrier_lds_only();   // flush reads done -> obuf reusable
    }
}

extern "C" void kernel_launch(void* const* d_in, const int* in_sizes, int n_in,
                              void* d_out, int out_size, void* d_ws, size_t ws_size,
                              hipStream_t stream) {
    const float* tau    = (const float*)d_in[0];
    const float* mu     = (const float*)d_in[1];
    const float* mu_bar = (const float*)d_in[2];
    const float* lw     = (const float*)d_in[3];
    const float* h2o    = (const float*)d_in[4];
    const float* o3     = (const float*)d_in[5];
    const float* co2    = (const float*)d_in[6];
    const float* uu     = (const float*)d_in[7];
    const float* n2o    = (const float*)d_in[8];
    const float* ch4    = (const float*)d_in[9];

    const float* Wd0 = (const float*)d_in[10];
    const float* bd0 = (const float*)d_in[11];
    const float* Wf0 = (const float*)d_in[12];
    const float* bf0 = (const float*)d_in[13];
    const float* Wd1 = (const float*)d_in[14];
    const float* bd1 = (const float*)d_in[15];
    const float* Wf1 = (const float*)d_in[16];
    const float* bf1 = (const float*)d_in[17];
    const float* Wd2 = (const float*)d_in[18];
    const float* bd2 = (const float*)d_in[19];
    const float* Wf2 = (const float*)d_in[20];
    const float* bf2 = (const float*)d_in[21];
    const float* Wd3 = (const float*)d_in[22];
    const float* bd3 = (const float*)d_in[23];
    const float* Wf3 = (const float*)d_in[24];
    const float* bf3 = (const float*)d_in[25];

    float* out = (float*)d_out;
    int N = in_sizes[1];  // mu has N elements

    int blocks = (N + SPB - 1) / SPB;
    lps_kernel<<<blocks, 512, 0, stream>>>(
        tau, mu, mu_bar, lw, h2o, o3, co2, uu, n2o, ch4,
        Wd0, bd0, Wf0, bf0, Wd1, bd1, Wf1, bf1,
        Wd2, bd2, Wf2, bf2, Wd3, bd3, Wf3, bf3,
        out, N);
}

// Round 12
// 80.212 us; speedup vs baseline: 6.0136x; 1.0145x over previous
//
#include <hip/hip_runtime.h>

#define EPS 1e-7f
#define NCH 29
#define SPB 128          // samples per block: 64 lanes x 2 packed (group0, group1)
#define ROWA 17          // padded float4 stride per sample in chunk staging buffer

// MLP sizes: 7 -> 5 -> 4 -> 4 -> 3, per-channel weights.
// W0: [c][7][5]  b0: [c][5]
// W1: [c][5][4]  b1: [c][4]
// W2: [c][4][4]  b2: [c][4]
// W3: [c][4][3]  b3: [c][3]

typedef float f32x2 __attribute__((ext_vector_type(2)));

__device__ __forceinline__ f32x2 splat2(float v) { f32x2 r; r.x = v; r.y = v; return r; }
__device__ __forceinline__ f32x2 fma2(f32x2 a, f32x2 b, f32x2 c) {
    return __builtin_elementwise_fma(a, b, c);
}
__device__ __forceinline__ f32x2 max2(f32x2 a, f32x2 b) {
    return __builtin_elementwise_max(a, b);
}
__device__ __forceinline__ f32x2 expc2(f32x2 a) {
    f32x2 r; r.x = __expf(a.x); r.y = __expf(a.y); return r;
}
__device__ __forceinline__ f32x2 rcp2(f32x2 a) {
    f32x2 r; r.x = __builtin_amdgcn_rcpf(a.x); r.y = __builtin_amdgcn_rcpf(a.y); return r;
}

// Barrier ordering LDS traffic only (lgkmcnt), NOT global stores (vmcnt):
// chunk-k stores stay in flight underneath chunk-(k+1) compute.
__device__ __forceinline__ void barrier_lds_only() {
    asm volatile("s_waitcnt lgkmcnt(0)\n\ts_barrier" ::: "memory");
}

// Packed 2-sample MLP: weights wave-uniform (SGPR), data f32x2 -> v_pk_fma_f32.
__device__ __forceinline__ void mlp7p(const f32x2 x[7],
    const float* __restrict__ W0, const float* __restrict__ b0,
    const float* __restrict__ W1, const float* __restrict__ b1,
    const float* __restrict__ W2, const float* __restrict__ b2,
    const float* __restrict__ W3, const float* __restrict__ b3,
    f32x2 e[3])
{
    const f32x2 zero = splat2(0.0f);
    f32x2 h0[5];
#pragma unroll
    for (int h = 0; h < 5; ++h) {
        f32x2 a = splat2(b0[h]);
#pragma unroll
        for (int f = 0; f < 7; ++f) a = fma2(x[f], splat2(W0[f * 5 + h]), a);
        h0[h] = max2(a, zero);
    }
    f32x2 h1[4];
#pragma unroll
    for (int k = 0; k < 4; ++k) {
        f32x2 a = splat2(b1[k]);
#pragma unroll
        for (int h = 0; h < 5; ++h) a = fma2(h0[h], splat2(W1[h * 4 + k]), a);
        h1[k] = max2(a, zero);
    }
    f32x2 h2[4];
#pragma unroll
    for (int k = 0; k < 4; ++k) {
        f32x2 a = splat2(b2[k]);
#pragma unroll
        for (int h = 0; h < 4; ++h) a = fma2(h1[h], splat2(W2[h * 4 + k]), a);
        h2[k] = max2(a, zero);
    }
    f32x2 l[3];
#pragma unroll
    for (int k = 0; k < 3; ++k) {
        f32x2 a = splat2(b3[k]);
#pragma unroll
        for (int h = 0; h < 4; ++h) a = fma2(h2[h], splat2(W3[h * 3 + k]), a);
        l[k] = a;
    }
    f32x2 m = max2(l[0], max2(l[1], l[2]));
    f32x2 e0 = expc2(l[0] - m);
    f32x2 e1 = expc2(l[1] - m);
    f32x2 e2 = expc2(l[2] - m);
    f32x2 rs = rcp2(e0 + e1 + e2);
    e[0] = e0 * rs; e[1] = e1 * rs; e[2] = e2 * rs;
}

// min 6 waves/EU -> VGPR cap 85 -> 24 waves/CU (3 blocks x 8 waves; LDS 34.8KB x3 fits 160KB)
__global__ __launch_bounds__(512, 6) void lps_kernel(
    const float* __restrict__ tau, const float* __restrict__ mu, const float* __restrict__ mu_bar,
    const float* __restrict__ lw, const float* __restrict__ h2o, const float* __restrict__ o3,
    const float* __restrict__ co2, const float* __restrict__ uu, const float* __restrict__ n2o,
    const float* __restrict__ ch4,
    const float* __restrict__ Wd0, const float* __restrict__ bd0,
    const float* __restrict__ Wf0, const float* __restrict__ bf0,
    const float* __restrict__ Wd1, const float* __restrict__ bd1,
    const float* __restrict__ Wf1, const float* __restrict__ bf1,
    const float* __restrict__ Wd2, const float* __restrict__ bd2,
    const float* __restrict__ Wf2, const float* __restrict__ bf2,
    const float* __restrict__ Wd3, const float* __restrict__ bd3,
    const float* __restrict__ Wf3, const float* __restrict__ bf3,
    float* __restrict__ out, int N)
{
    __shared__ __align__(16) float4 obuf[SPB * ROWA];   // 34816 B

    const int tid  = threadIdx.x;
    const int lane = tid & 63;
    const int wid  = __builtin_amdgcn_readfirstlane(tid >> 6);   // 0..7

    const long long base = (long long)blockIdx.x * SPB;
    const int s0 = (int)base + lane;
    const int s1 = s0 + 64;
    const int i0 = (s0 < N) ? s0 : (N - 1);
    const int i1 = (s1 < N) ? s1 : (N - 1);

    f32x2 mu2, mub2;
    mu2.x  = mu[i0];      mu2.y  = mu[i1];
    mub2.x = mu_bar[i0];  mub2.y = mu_bar[i1];
    const f32x2 rmu2  = rcp2(mu2 + splat2(EPS));
    const f32x2 rmub2 = rcp2(mub2 + splat2(EPS));

    // Persistent per-lane state kept minimal (register diet for 24 waves/CU):
    // cons2[7] + rmu2 + rmub2; scaled inputs are recomputed per chunk.
    f32x2 cons2[7];
    cons2[0].x = lw[i0];  cons2[0].y = lw[i1];
    cons2[1].x = h2o[i0]; cons2[1].y = h2o[i1];
    cons2[2].x = o3[i0];  cons2[2].y = o3[i1];
    cons2[3].x = co2[i0]; cons2[3].y = co2[i1];
    cons2[4].x = uu[i0];  cons2[4].y = uu[i1];
    cons2[5].x = n2o[i0]; cons2[5].y = n2o[i1];
    cons2[6].x = ch4[i0]; cons2[6].y = ch4[i1];

    int nsamp = N - (int)base;
    if (nsamp > SPB) nsamp = SPB;
    float4* out4 = (float4*)out;

    // 4 chunk-phases: compute 8 channels -> lgkm barrier -> issue stores ->
    // lgkm barrier -> next compute. No vmcnt drain anywhere.
#pragma unroll
    for (int k = 0; k < 4; ++k) {
        const int c = k * 8 + wid;            // wave-uniform channel
        if (c < NCH) {
            f32x2 tau2;
            tau2.x = tau[(size_t)i0 * NCH + c];
            tau2.y = tau[(size_t)i1 * NCH + c];
            const f32x2 td2 = expc2(-(tau2 * rmu2));
            const f32x2 tf2 = expc2(-(tau2 * rmub2));

            f32x2 x2[7];
            f32x2 ed[3], ef[3];
#pragma unroll
            for (int f = 0; f < 7; ++f) x2[f] = cons2[f] * rmu2;
            mlp7p(x2, Wd0 + c * 35, bd0 + c * 5, Wd1 + c * 20, bd1 + c * 4,
                      Wd2 + c * 16, bd2 + c * 4, Wd3 + c * 12, bd3 + c * 3, ed);
#pragma unroll
            for (int f = 0; f < 7; ++f) x2[f] = cons2[f] * rmub2;
            mlp7p(x2, Wf0 + c * 35, bf0 + c * 5, Wf1 + c * 20, bf1 + c * 4,
                      Wf2 + c * 16, bf2 + c * 4, Wf3 + c * 12, bf3 + c * 3, ef);

            const int r = (c - k * 8) * 2;    // local slot 0..15
            obuf[lane * ROWA + r]            = make_float4(td2.x, tf2.x, ed[0].x, ed[1].x);
            obuf[lane * ROWA + r + 1]        = make_float4(ed[2].x, ef[0].x, ef[1].x, ef[2].x);
            obuf[(lane + 64) * ROWA + r]     = make_float4(td2.y, tf2.y, ed[0].y, ed[1].y);
            obuf[(lane + 64) * ROWA + r + 1] = make_float4(ed[2].y, ef[0].y, ef[1].y, ef[2].y);
        }

        barrier_lds_only();

        // issue chunk-k stores (fire-and-forget)
        if (nsamp > 0) {
            if (k < 3) {
                const int tot = nsamp * 16;
                for (int i = tid; i < tot; i += 512) {
                    const int s = i >> 4, rr = i & 15;
                    out4[(base + s) * 58 + k * 16 + rr] = obuf[s * ROWA + rr];
                }
            } else {
                const int tot = nsamp * 10;   // 5 channels -> 10 f4 per sample
                for (int i = tid; i < tot; i += 512) {
                    const int s = i / 10, rr = i - s * 10;
                    out4[(base + s) * 58 + 48 + rr] = obuf[s * ROWA + rr];
                }
            }
        }

        barrier_lds_only();   // flush reads done -> obuf reusable
    }
}

extern "C" void kernel_launch(void* const* d_in, const int* in_sizes, int n_in,
                              void* d_out, int out_size, void* d_ws, size_t ws_size,
                              hipStream_t stream) {
    const float* tau    = (const float*)d_in[0];
    const float* mu     = (const float*)d_in[1];
    const float* mu_bar = (const float*)d_in[2];
    const float* lw     = (const float*)d_in[3];
    const float* h2o    = (const float*)d_in[4];
    const float* o3     = (const float*)d_in[5];
    const float* co2    = (const float*)d_in[6];
    const float* uu     = (const float*)d_in[7];
    const float* n2o    = (const float*)d_in[8];
    const float* ch4    = (const float*)d_in[9];

    const float* Wd0 = (const float*)d_in[10];
    const float* bd0 = (const float*)d_in[11];
    const float* Wf0 = (const float*)d_in[12];
    const float* bf0 = (const float*)d_in[13];
    const float* Wd1 = (const float*)d_in[14];
    const float* bd1 = (const float*)d_in[15];
    const float* Wf1 = (const float*)d_in[16];
    const float* bf1 = (const float*)d_in[17];
    const float* Wd2 = (const float*)d_in[18];
    const float* bd2 = (const float*)d_in[19];
    const float* Wf2 = (const float*)d_in[20];
    const float* bf2 = (const float*)d_in[21];
    const float* Wd3 = (const float*)d_in[22];
    const float* bd3 = (const float*)d_in[23];
    const float* Wf3 = (const float*)d_in[24];
    const float* bf3 = (const float*)d_in[25];

    float* out = (float*)d_out;
    int N = in_sizes[1];  // mu has N elements

    int blocks = (N + SPB - 1) / SPB;
    lps_kernel<<<blocks, 512, 0, stream>>>(
        tau, mu, mu_bar, lw, h2o, o3, co2, uu, n2o, ch4,
        Wd0, bd0, Wf0, bf0, Wd1, bd1, Wf1, bf1,
        Wd2, bd2, Wf2, bf2, Wd3, bd3, Wf3, bf3,
        out, N);
}